// Round 9
// baseline (69.924 us; speedup 1.0000x reference)
//
#include <hip/hip_runtime.h>
#include <hip/hip_bf16.h>

#define N_NODES 4096            // row key == global src node id (g<<7)|r
#define N_PER   128
#define D_DIM   64
#define CELLS   (N_NODES * N_PER)   // 524288
#define CAP     12              // per-cell edge capacity; Poisson(0.25), P(>12)~1e-12

// Fused init + projection.
// blocks [0,512): zero cnt_pack (131072 int4).
// blocks [512,1536): p1[n][d] = b[d] + x[n]·W[d][0:64]; p2[n][d] = x[n]·W[d][64:128].
__global__ void init_proj(int4* __restrict__ cp4,
                          const float* __restrict__ x,
                          const float* __restrict__ W,
                          const float* __restrict__ b,
                          float* __restrict__ p1,
                          float* __restrict__ p2) {
    if (blockIdx.x < 512) {
        int i = blockIdx.x * 256 + threadIdx.x;
        cp4[i] = make_int4(0, 0, 0, 0);
    } else {
        int n = (blockIdx.x - 512) * 4 + (threadIdx.x >> 6);
        int d = threadIdx.x & 63;
        const float* xr = x + (size_t)n * D_DIM;
        const float* w  = W + (size_t)d * (2 * D_DIM);
        float a1 = b[d];
        float a2 = 0.0f;
#pragma unroll
        for (int k = 0; k < D_DIM; ++k) {
            float xv = xr[k];
            a1 += xv * w[k];
            a2 += xv * w[D_DIM + k];
        }
        p1[(size_t)n * D_DIM + d] = a1;
        p2[(size_t)n * D_DIM + d] = a2;
    }
}

// cnt_pack[cell] = token_count | (edge_count<<16).
// Edges: slot = old edge count; store edge id in cslots[cell*CAP+slot].
// Tokens: +1 on low half (token value is cell-determined: p1[row]+p2[col]).
__global__ void link(const int* __restrict__ esrc,
                     const int* __restrict__ edst,
                     const int* __restrict__ tsrc,
                     const int* __restrict__ tdst,
                     int* __restrict__ cnt_pack,
                     int* __restrict__ cslots,
                     int E, int total) {
    int i = blockIdx.x * blockDim.x + threadIdx.x;
    if (i >= total) return;
    if (i < E) {
        int s = esrc[i];                        // 0..4095
        int cell = (s << 7) | (edst[i] & 127);
        int old = atomicAdd(&cnt_pack[cell], 0x10000);
        int slot = old >> 16;
        if (slot < CAP) cslots[(size_t)cell * CAP + slot] = i;
    } else {
        int j = i - E;
        int cell = (tsrc[j] << 7) | (tdst[j] & 127);
        atomicAdd(&cnt_pack[cell], 1);
    }
}

// One block per row k. No LDS, no barriers. Each 16-lane group owns one cell
// per iteration: v = tok*(p1[k]+p2[col]) + sum attr[slots] in a float4 reg,
// stored straight to global (4 consecutive c-rows per wave = 1KB contiguous).
__global__ void __launch_bounds__(256, 8)
row_write(const int* __restrict__ cnt_pack,
          const int* __restrict__ cslots,
          const float4* __restrict__ attr4,
          const float4* __restrict__ p14,
          const float4* __restrict__ p24,
          float4* __restrict__ out4) {
    const int k      = blockIdx.x;             // row key (g<<7)|r
    const int gbase  = k & ~127;               // g<<7
    const int wave   = threadIdx.x >> 6;       // 0..3
    const int grp    = (threadIdx.x >> 4) & 3;
    const int lane16 = threadIdx.x & 15;
    const int cbase  = wave * 32;

    float4 p1v = p14[(size_t)k * 16 + lane16];

    // Hoist the 8 packed counts (independent dword loads, all in flight).
    int pk[8];
#pragma unroll
    for (int it = 0; it < 8; ++it)
        pk[it] = cnt_pack[(k << 7) + cbase + it * 4 + grp];

#pragma unroll
    for (int it = 0; it < 8; ++it) {
        int c    = cbase + it * 4 + grp;
        int cell = (k << 7) | c;
        float f  = (float)(pk[it] & 0xFFFF);
        float4 p2v = p24[(size_t)(gbase | c) * 16 + lane16];
        float4 v;
        v.x = f * (p1v.x + p2v.x);
        v.y = f * (p1v.y + p2v.y);
        v.z = f * (p1v.z + p2v.z);
        v.w = f * (p1v.w + p2v.w);
        int n = pk[it] >> 16;
        if (n > CAP) n = CAP;
        const int* sl = cslots + (size_t)cell * CAP;
        for (int i = 0; i < n; ++i) {          // avg 0.25 iterations
            int e = sl[i];                     // broadcast within group
            float4 a = attr4[(size_t)e * 16 + lane16];
            v.x += a.x; v.y += a.y; v.z += a.z; v.w += a.w;
        }
        out4[(size_t)cell * 16 + lane16] = v;  // 1KB contiguous per wave instr
    }
}

extern "C" void kernel_launch(void* const* d_in, const int* in_sizes, int n_in,
                              void* d_out, int out_size, void* d_ws, size_t ws_size,
                              hipStream_t stream) {
    const float* x           = (const float*)d_in[0];
    const int*   edge_index  = (const int*)d_in[1];
    const float* edge_attr   = (const float*)d_in[2];
    // d_in[3] = batch (unused: indices are intra-graph with N_PER=128 stride)
    const int*   token_index = (const int*)d_in[4];
    const float* W           = (const float*)d_in[5];
    const float* b           = (const float*)d_in[6];

    const int E = in_sizes[1] / 2;   // 131072
    const int T = in_sizes[4] / 2;   // 131072

    // Workspace layout (~28 MB of the 512 MiB ws):
    float* p1       = (float*)d_ws;                          // 1 MB
    float* p2       = p1 + (size_t)N_NODES * D_DIM;          // 1 MB
    int*   cnt_pack = (int*)(p2 + (size_t)N_NODES * D_DIM);  // 2 MB
    int*   cslots   = cnt_pack + CELLS;                      // 24 MB

    // 1. zero cnt_pack + projection.
    init_proj<<<1536, 256, 0, stream>>>((int4*)cnt_pack, x, W, b, p1, p2);

    // 2. per-cell edge slots + packed token/edge counts.
    int total = E + T;
    link<<<(total + 255) / 256, 256, 0, stream>>>(
        edge_index, edge_index + E, token_index, token_index + T,
        cnt_pack, cslots, E, total);

    // 3. one block per row: register accumulate, straight streaming stores.
    row_write<<<N_NODES, 256, 0, stream>>>(
        cnt_pack, cslots, (const float4*)edge_attr,
        (const float4*)p1, (const float4*)p2, (float4*)d_out);
}